// Round 4
// baseline (484.826 us; speedup 1.0000x reference)
//
#include <hip/hip_runtime.h>

#define N 8192
#define F 128
#define ALPHA 0.2f

typedef __attribute__((ext_vector_type(8))) short short8;
typedef __attribute__((ext_vector_type(4))) float f32x4;
typedef unsigned short u16;

__device__ __forceinline__ u16 f2bf(float f) {
    unsigned int u = __float_as_uint(f);
    u += 0x7fff + ((u >> 16) & 1);  // RNE; inputs are finite, no NaN handling needed
    return (u16)(u >> 16);
}

// ---------------- K1: h = x@W ; emit hT (bf16, [feature][node]) + ssrc/sdst (fp32) ----------------
__global__ __launch_bounds__(256) void gemm_h(const float* __restrict__ x,
                                              const float* __restrict__ W,
                                              const float* __restrict__ aa,
                                              u16* __restrict__ hT,
                                              float* __restrict__ ssrc,
                                              float* __restrict__ sdst) {
    __shared__ float xs[32 * 128];
    __shared__ float Wsh[32 * 128];
    const int t = threadIdx.x;
    const int i0 = blockIdx.x * 32;
    const int c4 = (t & 31) * 4;
    const int r8 = t >> 5;

#pragma unroll
    for (int p = 0; p < 4; ++p) {
        int rr = p * 8 + r8;
        *(float4*)&xs[rr * 128 + c4] = *(const float4*)&x[(size_t)(i0 + rr) * 128 + c4];
    }

    const int tx = t & 31, ty = t >> 5;
    const int r0 = ty * 4, c0 = tx * 4;
    float acc[4][4] = {};

    for (int kc = 0; kc < 4; ++kc) {
        __syncthreads();
#pragma unroll
        for (int p = 0; p < 4; ++p) {
            int k = p * 8 + r8;
            *(float4*)&Wsh[k * 128 + c4] = *(const float4*)&W[(kc * 32 + k) * 128 + c4];
        }
        __syncthreads();
#pragma unroll 4
        for (int k = 0; k < 32; k += 4) {
            float xr[4][4];
#pragma unroll
            for (int rr = 0; rr < 4; ++rr)
                *(float4*)xr[rr] = *(const float4*)&xs[(r0 + rr) * 128 + kc * 32 + k];
#pragma unroll
            for (int kk = 0; kk < 4; ++kk) {
                float4 wv = *(const float4*)&Wsh[(k + kk) * 128 + c0];
#pragma unroll
                for (int rr = 0; rr < 4; ++rr) {
                    acc[rr][0] += xr[rr][kk] * wv.x;
                    acc[rr][1] += xr[rr][kk] * wv.y;
                    acc[rr][2] += xr[rr][kk] * wv.z;
                    acc[rr][3] += xr[rr][kk] * wv.w;
                }
            }
        }
    }

    // epilogue 1: hT bf16 transposed store
#pragma unroll
    for (int rr = 0; rr < 4; ++rr)
#pragma unroll
        for (int cc = 0; cc < 4; ++cc)
            hT[(size_t)(c0 + cc) * N + (i0 + r0 + rr)] = f2bf(acc[rr][cc]);

    // epilogue 2: fused scores s_src/s_dst from full-precision accumulators
    float4 asv = *(const float4*)&aa[c0];
    float4 adv = *(const float4*)&aa[F + c0];
#pragma unroll
    for (int rr = 0; rr < 4; ++rr) {
        float vs = acc[rr][0] * asv.x + acc[rr][1] * asv.y + acc[rr][2] * asv.z + acc[rr][3] * asv.w;
        float vd = acc[rr][0] * adv.x + acc[rr][1] * adv.y + acc[rr][2] * adv.z + acc[rr][3] * adv.w;
#pragma unroll
        for (int off = 16; off >= 1; off >>= 1) {
            vs += __shfl_down(vs, off, 32);
            vd += __shfl_down(vd, off, 32);
        }
        if (tx == 0) {
            ssrc[i0 + r0 + rr] = vs;
            sdst[i0 + r0 + rr] = vd;
        }
    }
}

// exact counted-vmcnt wait; memory clobber pins all loop memory ops to their region
#define WAITVM(n) asm volatile("s_waitcnt vmcnt(" #n ")" ::: "memory")

// 16B/lane global->LDS DMA: per-lane global source, wave-uniform LDS base;
// HW writes base + lane*16 (linear). Zero VGPR cost for in-flight data.
__device__ __forceinline__ void dma16(const void* g, void* l) {
    __builtin_amdgcn_global_load_lds(
        (const __attribute__((address_space(1))) unsigned int*)g,
        (__attribute__((address_space(3))) unsigned int*)l, 16, 0, 0);
}

// ---------------- K2: fused attention, DMA-pipelined, barrier-free main loop ----------------
// Block = 4 independent waves over the SAME 16 i-rows; wave w owns j-quarter
// [w*2048,(w+1)*2048), all 128 features. Per 32-j chunk: 10 global_load_lds
// (8x B-frag 1KB slabs + 2x adj 1KB slabs) into the wave's PRIVATE double buffer.
// In-flight data lives in LDS, not VGPRs -> the register allocator cannot collapse
// the pipeline (round-2/3 failure: VGPR=64 forced load->wait->use serialization,
// ~8000 cyc/chunk). Counted vmcnt(12) per iteration = chunk c landed, chunk c+1
// (10 DMA + 2 sdst reg-loads) still in flight. No __syncthreads in the main loop.
__global__ __launch_bounds__(256, 2) void attn_fused(const int* __restrict__ adj,
                                                     const u16* __restrict__ hT,
                                                     const float* __restrict__ ssrc,
                                                     const float* __restrict__ sdst,
                                                     float* __restrict__ out) {
    __shared__ __align__(16) char ldsraw[4 * 20480];  // 80 KB: 4 waves x 2 bufs x 10 KB

    const int t = threadIdx.x;
    const int w = t >> 6, L = t & 63;
    const int quad = L >> 4, l16 = L & 15;
    const int tile0 = blockIdx.x * 16;     // grid.x = N/16 = 512
    const int prow = tile0 + l16;
    const int JW = N / 4;                  // 2048 cols per wave
    const int jbase = w * JW;
    const int NC = JW / 32;                // 64 chunks of 32 j

    char* ldsw = ldsraw + w * 20480;       // wave-private slab (uniform per wave)

    const float s_i = ssrc[prow];
    const int* pA = adj + (size_t)prow * N + jbase + quad * 8;
    const float* pD = sdst + jbase + quad * 8;
    const u16* pB = hT + (size_t)l16 * N + jbase + quad * 8;

    f32x4 acc[8];
#pragma unroll
    for (int cg = 0; cg < 8; ++cg) acc[cg] = 0.f;
    float rsum = 0.f;

    // 8 w values -> bf16 A-frag (v_cvt_pk_bf16_f32 RNE == f2bf) + exact bf16 rowsum
    auto mk_frag = [&](int4 a0, int4 a1, float4 d0, float4 d1) -> short8 {
        const int m[8] = {a0.x, a0.y, a0.z, a0.w, a1.x, a1.y, a1.z, a1.w};
        const float d[8] = {d0.x, d0.y, d0.z, d0.w, d1.x, d1.y, d1.z, d1.w};
        float wv[8];
#pragma unroll
        for (int k = 0; k < 8; ++k) {
            float z = s_i + d[k];
            float e = __expf(fmaxf(z, ALPHA * z));
            wv[k] = (m[k] > 0) ? e : 0.f;
        }
        union { unsigned int u[4]; short8 s8; } pk;
        float s = 0.f;
#pragma unroll
        for (int p = 0; p < 4; ++p) {
            unsigned int r;
            asm("v_cvt_pk_bf16_f32 %0, %1, %2" : "=v"(r) : "v"(wv[2 * p]), "v"(wv[2 * p + 1]));
            pk.u[p] = r;
            s += __uint_as_float(r << 16);
            s += __uint_as_float(r & 0xffff0000u);
        }
        rsum += s;
        return pk.s8;
    };

    // issue the 10 DMAs for chunk cc into buffer b (slabs: B cg*1KB, adj at +8K,+9K)
    auto issue_chunk = [&](int cc, int b) {
        const int coff = cc * 32;
        char* base = ldsw + b * 10240;
#pragma unroll
        for (int cg = 0; cg < 8; ++cg)
            dma16(pB + (size_t)cg * 16 * N + coff, base + cg * 1024);
        dma16(pA + coff, base + 8192);
        dma16(pA + coff + 4, base + 9216);
    };

    // ---- prologue: chunk 0 DMA; sdst chunks 0,1 in regs ----
    issue_chunk(0, 0);
    float4 D0x = *(const float4*)(pD);
    float4 D0y = *(const float4*)(pD + 4);
    float4 D1x = *(const float4*)(pD + 32);
    float4 D1y = *(const float4*)(pD + 36);

#pragma unroll 1
    for (int c = 0; c < NC; ++c) {
        // issue chunk c+1 (clamped tail re-DMA targets the already-consumed buffer: benign)
        const int cb = (c + 1 < NC) ? c + 1 : NC - 1;
        issue_chunk(cb, (c + 1) & 1);
        // sdst chunk c+2 (L2-hot, depth-2 register pipeline)
        const int cd = (c + 2 < NC) ? c + 2 : NC - 1;
        float4 nDx = *(const float4*)(pD + cd * 32);
        float4 nDy = *(const float4*)(pD + cd * 32 + 4);

        // chunk c's 12 ops retired; chunk c+1's 12 (10 DMA + 2 sdst) stay in flight
        WAITVM(12);
        __builtin_amdgcn_sched_barrier(0);

        const char* bb = ldsw + (c & 1) * 10240;
        int4 a0 = *(const int4*)(bb + 8192 + (size_t)L * 16);
        int4 a1 = *(const int4*)(bb + 9216 + (size_t)L * 16);
        short8 Bv[8];
#pragma unroll
        for (int cg = 0; cg < 8; ++cg)
            Bv[cg] = *(const short8*)(bb + cg * 1024 + (size_t)L * 16);

        short8 af = mk_frag(a0, a1, D0x, D0y);
#pragma unroll
        for (int cg = 0; cg < 8; ++cg)
            acc[cg] = __builtin_amdgcn_mfma_f32_16x16x32_bf16(af, Bv[cg], acc[cg], 0, 0, 0);

        D0x = D1x; D0y = D1y; D1x = nDx; D1y = nDy;
    }

    // drain all outstanding DMAs before aliasing the slabs with the reduce buffers
    WAITVM(0);
    __builtin_amdgcn_sched_barrier(0);

    // ---- epilogue: combine 4 j-quarters via LDS (aliased into own wave slab) ----
    rsum += __shfl_xor(rsum, 16);
    rsum += __shfl_xor(rsum, 32);   // all quads hold this quarter's row-sum for row l16
    float* acw = (float*)ldsw;               // [16][132] = 8448 B (aliases buf0; drained)
    float* srw = (float*)(ldsw + 8448);      // 16 floats
    if (L < 16) srw[l16] = rsum;

    // D layout: col = l&15, row = quad*4 + reg
#pragma unroll
    for (int cg = 0; cg < 8; ++cg)
#pragma unroll
        for (int r = 0; r < 4; ++r)
            acw[(quad * 4 + r) * 132 + cg * 16 + l16] = acc[cg][r];

    __syncthreads();

#pragma unroll
    for (int p = 0; p < 2; ++p) {
        const int fid = t * 2 + p;          // 0..511 -> 16 rows x 32 float4-cols
        const int row = fid >> 5;
        const int c4 = (fid & 31) * 4;
        float inv = 0.f;
        float4 o = {0.f, 0.f, 0.f, 0.f};
#pragma unroll
        for (int wv = 0; wv < 4; ++wv) {
            const float* aw = (const float*)(ldsraw + wv * 20480);
            float4 s = *(const float4*)&aw[row * 132 + c4];
            o.x += s.x; o.y += s.y; o.z += s.z; o.w += s.w;
            inv += ((const float*)(ldsraw + wv * 20480 + 8448))[row];
        }
        inv = 1.0f / inv;
        o.x *= inv; o.y *= inv; o.z *= inv; o.w *= inv;
        *(float4*)&out[(size_t)(tile0 + row) * F + c4] = o;
    }
}

extern "C" void kernel_launch(void* const* d_in, const int* in_sizes, int n_in,
                              void* d_out, int out_size, void* d_ws, size_t ws_size,
                              hipStream_t stream) {
    (void)in_sizes; (void)n_in; (void)out_size; (void)ws_size;
    const float* x   = (const float*)d_in[0];
    const int*   adj = (const int*)d_in[1];
    const float* W   = (const float*)d_in[2];
    const float* a   = (const float*)d_in[3];
    float* out = (float*)d_out;

    u16* hT     = (u16*)d_ws;                    // N*F bf16 (2 MB)
    float* ssrc = (float*)(hT + (size_t)N * F);  // N
    float* sdst = ssrc + N;                      // N

    gemm_h<<<N / 32, 256, 0, stream>>>(x, W, a, hT, ssrc, sdst);
    attn_fused<<<N / 16, 256, 0, stream>>>(adj, hT, ssrc, sdst, out);
}

// Round 5
// 423.934 us; speedup vs baseline: 1.1436x; 1.1436x over previous
//
#include <hip/hip_runtime.h>

#define N 8192
#define F 128
#define ALPHA 0.2f
#define NSPLIT 4

typedef __attribute__((ext_vector_type(8))) short short8;
typedef __attribute__((ext_vector_type(4))) float f32x4;
typedef unsigned short u16;

__device__ __forceinline__ u16 f2bf(float f) {
    unsigned int u = __float_as_uint(f);
    u += 0x7fff + ((u >> 16) & 1);  // RNE; inputs are finite, no NaN handling needed
    return (u16)(u >> 16);
}

// ---------------- K1: h = x@W ; emit hT (bf16, [feature][node]) + ssrc/sdst (fp32) ----------------
__global__ __launch_bounds__(256) void gemm_h(const float* __restrict__ x,
                                              const float* __restrict__ W,
                                              const float* __restrict__ aa,
                                              u16* __restrict__ hT,
                                              float* __restrict__ ssrc,
                                              float* __restrict__ sdst) {
    __shared__ float xs[32 * 128];
    __shared__ float Wsh[32 * 128];
    const int t = threadIdx.x;
    const int i0 = blockIdx.x * 32;
    const int c4 = (t & 31) * 4;
    const int r8 = t >> 5;

#pragma unroll
    for (int p = 0; p < 4; ++p) {
        int rr = p * 8 + r8;
        *(float4*)&xs[rr * 128 + c4] = *(const float4*)&x[(size_t)(i0 + rr) * 128 + c4];
    }

    const int tx = t & 31, ty = t >> 5;
    const int r0 = ty * 4, c0 = tx * 4;
    float acc[4][4] = {};

    for (int kc = 0; kc < 4; ++kc) {
        __syncthreads();
#pragma unroll
        for (int p = 0; p < 4; ++p) {
            int k = p * 8 + r8;
            *(float4*)&Wsh[k * 128 + c4] = *(const float4*)&W[(kc * 32 + k) * 128 + c4];
        }
        __syncthreads();
#pragma unroll 4
        for (int k = 0; k < 32; k += 4) {
            float xr[4][4];
#pragma unroll
            for (int rr = 0; rr < 4; ++rr)
                *(float4*)xr[rr] = *(const float4*)&xs[(r0 + rr) * 128 + kc * 32 + k];
#pragma unroll
            for (int kk = 0; kk < 4; ++kk) {
                float4 wv = *(const float4*)&Wsh[(k + kk) * 128 + c0];
#pragma unroll
                for (int rr = 0; rr < 4; ++rr) {
                    acc[rr][0] += xr[rr][kk] * wv.x;
                    acc[rr][1] += xr[rr][kk] * wv.y;
                    acc[rr][2] += xr[rr][kk] * wv.z;
                    acc[rr][3] += xr[rr][kk] * wv.w;
                }
            }
        }
    }

    // epilogue 1: hT bf16 transposed store
#pragma unroll
    for (int rr = 0; rr < 4; ++rr)
#pragma unroll
        for (int cc = 0; cc < 4; ++cc)
            hT[(size_t)(c0 + cc) * N + (i0 + r0 + rr)] = f2bf(acc[rr][cc]);

    // epilogue 2: fused scores s_src/s_dst from full-precision accumulators
    float4 asv = *(const float4*)&aa[c0];
    float4 adv = *(const float4*)&aa[F + c0];
#pragma unroll
    for (int rr = 0; rr < 4; ++rr) {
        float vs = acc[rr][0] * asv.x + acc[rr][1] * asv.y + acc[rr][2] * asv.z + acc[rr][3] * asv.w;
        float vd = acc[rr][0] * adv.x + acc[rr][1] * adv.y + acc[rr][2] * adv.z + acc[rr][3] * adv.w;
#pragma unroll
        for (int off = 16; off >= 1; off >>= 1) {
            vs += __shfl_down(vs, off, 32);
            vd += __shfl_down(vd, off, 32);
        }
        if (tx == 0) {
            ssrc[i0 + r0 + rr] = vs;
            sdst[i0 + r0 + rr] = vd;
        }
    }
}

// ---------------- K2: attention via bf16 MFMA, 64-i-row blocks ----------------
// Round-0 structure (proven fastest delivery rate) with the i-tile doubled to cut hT
// traffic 2x: block = 64 i-rows, 4 waves, 1/4 of j. Wave w (ks=w&1, rp=w>>1) produces
// TWO A-frag-sets per chunk (row-tiles 2rp, 2rp+1 at k-seg ks) from adj in-lane;
// consumes all 8 frag-sets for its 32 feature cols [w*32, w*32+32).
__global__ __launch_bounds__(256, 2) void attn_mfma(const int* __restrict__ adj,
                                                    const u16* __restrict__ hT,
                                                    const float* __restrict__ ssrc,
                                                    const float* __restrict__ sdst,
                                                    float* __restrict__ out,
                                                    float* __restrict__ pacc,
                                                    float* __restrict__ pS) {
    __shared__ short8 wsh[2][8][64];   // 16 KB: [buf][frag-set rt*2+ks][lane]
    __shared__ float srow[4][2][16];   // [rt][ks][l16]

    const int t = threadIdx.x;
    const int w = t >> 6, L = t & 63;
    const int quad = L >> 4, l16 = L & 15;
    const int i0 = blockIdx.x * 64;     // grid.x = N/64 = 128
    const int split = blockIdx.y;       // 4 j-splits
    const int JW = N / NSPLIT;          // 2048
    const int jbase = split * JW;
    const int NC = JW / 64;             // 32 chunks of 64 j

    const int ks = w & 1, rp = w >> 1;
    const int prow0 = i0 + (rp * 2 + 0) * 16 + l16;
    const int prow1 = i0 + (rp * 2 + 1) * 16 + l16;
    const float s0 = ssrc[prow0];
    const float s1 = ssrc[prow1];

    const int* pA0 = adj + (size_t)prow0 * N + jbase + ks * 32 + quad * 8;
    const int* pA1 = adj + (size_t)prow1 * N + jbase + ks * 32 + quad * 8;
    const float* pD = sdst + jbase + ks * 32 + quad * 8;
    const u16* pB = hT + (size_t)(w * 32 + l16) * N + jbase + quad * 8;

    f32x4 acc[2][4];   // [c2 feature-half][rt row-tile]
#pragma unroll
    for (int a = 0; a < 2; ++a)
#pragma unroll
        for (int b = 0; b < 4; ++b) acc[a][b] = 0.f;
    float rs0 = 0.f, rs1 = 0.f;

    // 8 w values -> bf16 frag (v_cvt_pk_bf16_f32 RNE == f2bf) + exact bf16 rowsum
    auto cw = [&](int buf, int fragid, float s_i, float& rsum,
                  int4 a0, int4 a1, float4 d0, float4 d1) {
        const int m[8] = {a0.x, a0.y, a0.z, a0.w, a1.x, a1.y, a1.z, a1.w};
        const float d[8] = {d0.x, d0.y, d0.z, d0.w, d1.x, d1.y, d1.z, d1.w};
        float wv[8];
#pragma unroll
        for (int k = 0; k < 8; ++k) {
            float z = s_i + d[k];
            float e = __expf(fmaxf(z, ALPHA * z));
            wv[k] = (m[k] > 0) ? e : 0.f;
        }
        union { unsigned int u[4]; short8 s8; } pk;
        float s = 0.f;
#pragma unroll
        for (int p = 0; p < 4; ++p) {
            unsigned int r;
            asm("v_cvt_pk_bf16_f32 %0, %1, %2" : "=v"(r) : "v"(wv[2 * p]), "v"(wv[2 * p + 1]));
            pk.u[p] = r;
            s += __uint_as_float(r << 16);
            s += __uint_as_float(r & 0xffff0000u);
        }
        rsum += s;
        wsh[buf][fragid][L] = pk.s8;
    };

    const int f0 = (rp * 2 + 0) * 2 + ks;   // fragid of row-tile 2rp
    const int f1 = (rp * 2 + 1) * 2 + ks;   // fragid of row-tile 2rp+1

    // ---- prologue: chunk 0 ----
    int4 aN00 = *(const int4*)(pA0);     int4 aN01 = *(const int4*)(pA0 + 4);
    int4 aN10 = *(const int4*)(pA1);     int4 aN11 = *(const int4*)(pA1 + 4);
    float4 dN0 = *(const float4*)(pD);   float4 dN1 = *(const float4*)(pD + 4);
    cw(0, f0, s0, rs0, aN00, aN01, dN0, dN1);
    cw(0, f1, s1, rs1, aN10, aN11, dN0, dN1);

    short8 Bbuf[2][2];
#pragma unroll
    for (int c2 = 0; c2 < 2; ++c2)
#pragma unroll
        for (int kb = 0; kb < 2; ++kb)
            Bbuf[c2][kb] = *(const short8*)(pB + (size_t)(c2 * 16) * N + kb * 32);

    // prefetch chunk 1 adj/sdst
    aN00 = *(const int4*)(pA0 + 64);  aN01 = *(const int4*)(pA0 + 68);
    aN10 = *(const int4*)(pA1 + 64);  aN11 = *(const int4*)(pA1 + 68);
    dN0 = *(const float4*)(pD + 64);  dN1 = *(const float4*)(pD + 68);

    for (int c = 1; c < NC; ++c) {
        __syncthreads();  // wsh[(c-1)&1] ready; buf (c&1) readers (chunk c-2) long done
        const int coff = c * 64;

        // B(c) loads in flight across this iteration (consumed next iter / epilogue)
        short8 Bload[2][2];
#pragma unroll
        for (int c2 = 0; c2 < 2; ++c2)
#pragma unroll
            for (int kb = 0; kb < 2; ++kb)
                Bload[c2][kb] = *(const short8*)(pB + (size_t)(c2 * 16) * N + kb * 32 + coff);

        // prefetch adj/sdst for chunk c+1 (clamped; redundant final load is harmless)
        const int cn = (c + 1 < NC) ? c + 1 : NC - 1;
        int4 aP00 = *(const int4*)(pA0 + cn * 64);  int4 aP01 = *(const int4*)(pA0 + cn * 64 + 4);
        int4 aP10 = *(const int4*)(pA1 + cn * 64);  int4 aP11 = *(const int4*)(pA1 + cn * 64 + 4);
        float4 dP0 = *(const float4*)(pD + cn * 64);
        float4 dP1 = *(const float4*)(pD + cn * 64 + 4);

        // MFMA chunk c-1 (16 MFMAs: 2 feature-halves x 4 row-tiles x 2 k-segs)
        short8 af[8];
#pragma unroll
        for (int fs = 0; fs < 8; ++fs) af[fs] = wsh[(c - 1) & 1][fs][L];
#pragma unroll
        for (int c2 = 0; c2 < 2; ++c2)
#pragma unroll
            for (int rt = 0; rt < 4; ++rt)
#pragma unroll
                for (int kb = 0; kb < 2; ++kb)
                    acc[c2][rt] = __builtin_amdgcn_mfma_f32_16x16x32_bf16(
                        af[rt * 2 + kb], Bbuf[c2][kb], acc[c2][rt], 0, 0, 0);

        // w(c) from regs loaded last iteration
        cw(c & 1, f0, s0, rs0, aN00, aN01, dN0, dN1);
        cw(c & 1, f1, s1, rs1, aN10, aN11, dN0, dN1);

        // rotate
        aN00 = aP00; aN01 = aP01; aN10 = aP10; aN11 = aP11;
        dN0 = dP0; dN1 = dP1;
#pragma unroll
        for (int c2 = 0; c2 < 2; ++c2)
#pragma unroll
            for (int kb = 0; kb < 2; ++kb) Bbuf[c2][kb] = Bload[c2][kb];
    }

    // ---- epilogue: MFMA last chunk ----
    __syncthreads();
    {
        short8 af[8];
#pragma unroll
        for (int fs = 0; fs < 8; ++fs) af[fs] = wsh[(NC - 1) & 1][fs][L];
#pragma unroll
        for (int c2 = 0; c2 < 2; ++c2)
#pragma unroll
            for (int rt = 0; rt < 4; ++rt)
#pragma unroll
                for (int kb = 0; kb < 2; ++kb)
                    acc[c2][rt] = __builtin_amdgcn_mfma_f32_16x16x32_bf16(
                        af[rt * 2 + kb], Bbuf[c2][kb], acc[c2][rt], 0, 0, 0);
    }

    // store partials: D layout col=lane&15, row=quad*4+reg
    float* dst = split ? pacc + (size_t)(split - 1) * N * F : out;
#pragma unroll
    for (int c2 = 0; c2 < 2; ++c2) {
        const int col = w * 32 + c2 * 16 + l16;
#pragma unroll
        for (int rt = 0; rt < 4; ++rt) {
            const int row0 = i0 + rt * 16 + quad * 4;
#pragma unroll
            for (int r = 0; r < 4; ++r)
                dst[(size_t)(row0 + r) * F + col] = acc[c2][rt][r];
        }
    }

    // row sums: butterfly over quads, then combine the two ks-waves via LDS
    rs0 += __shfl_xor(rs0, 16);
    rs0 += __shfl_xor(rs0, 32);
    rs1 += __shfl_xor(rs1, 16);
    rs1 += __shfl_xor(rs1, 32);
    if (L < 16) {
        srow[rp * 2 + 0][ks][l16] = rs0;
        srow[rp * 2 + 1][ks][l16] = rs1;
    }
    __syncthreads();
    if (t < 64) pS[split * N + i0 + t] = srow[t >> 4][0][t & 15] + srow[t >> 4][1][t & 15];
}

// ---------------- K3: out = (out + pacc0 + pacc1 + pacc2) / (sum of 4 pS) ----------------
__global__ __launch_bounds__(256) void finalize(float* __restrict__ out,
                                                const float* __restrict__ pacc,
                                                const float* __restrict__ pS) {
    const int idx = (blockIdx.x * 256 + threadIdx.x) * 4;
    const int i = idx >> 7;
    const float inv = 1.0f / (pS[i] + pS[N + i] + pS[2 * N + i] + pS[3 * N + i]);
    float4 a0 = *(const float4*)&out[idx];
    float4 a1 = *(const float4*)&pacc[idx];
    float4 a2 = *(const float4*)&pacc[(size_t)N * F + idx];
    float4 a3 = *(const float4*)&pacc[2 * (size_t)N * F + idx];
    float4 o = {(a0.x + a1.x + a2.x + a3.x) * inv,
                (a0.y + a1.y + a2.y + a3.y) * inv,
                (a0.z + a1.z + a2.z + a3.z) * inv,
                (a0.w + a1.w + a2.w + a3.w) * inv};
    *(float4*)&out[idx] = o;
}

extern "C" void kernel_launch(void* const* d_in, const int* in_sizes, int n_in,
                              void* d_out, int out_size, void* d_ws, size_t ws_size,
                              hipStream_t stream) {
    (void)in_sizes; (void)n_in; (void)out_size; (void)ws_size;
    const float* x   = (const float*)d_in[0];
    const int*   adj = (const int*)d_in[1];
    const float* W   = (const float*)d_in[2];
    const float* a   = (const float*)d_in[3];
    float* out = (float*)d_out;

    u16* hT     = (u16*)d_ws;                    // N*F bf16 (2 MB)
    float* ssrc = (float*)(hT + (size_t)N * F);  // N
    float* sdst = ssrc + N;                      // N
    float* pS   = sdst + N;                      // NSPLIT*N
    float* pacc = pS + NSPLIT * N;               // (NSPLIT-1)*N*F fp32 (12 MB)

    gemm_h<<<N / 32, 256, 0, stream>>>(x, W, a, hT, ssrc, sdst);
    attn_mfma<<<dim3(N / 64, NSPLIT), 256, 0, stream>>>(adj, hT, ssrc, sdst, out, pacc, pS);
    finalize<<<(N * F / 4) / 256, 256, 0, stream>>>(out, pacc, pS);
}

// Round 6
// 413.546 us; speedup vs baseline: 1.1724x; 1.0251x over previous
//
#include <hip/hip_runtime.h>

#define N 8192
#define F 128
#define ALPHA 0.2f

typedef __attribute__((ext_vector_type(8))) short short8;
typedef __attribute__((ext_vector_type(4))) float f32x4;
typedef unsigned short u16;

__device__ __forceinline__ u16 f2bf(float f) {
    unsigned int u = __float_as_uint(f);
    u += 0x7fff + ((u >> 16) & 1);  // RNE; inputs are finite, no NaN handling needed
    return (u16)(u >> 16);
}
__device__ __forceinline__ float lrelu(float z) { return fmaxf(z, ALPHA * z); }

// ---------------- K1: h = x@W ; emit hT (bf16, [feature][node]) + ssrc/sdst (fp32) ----------------
__global__ __launch_bounds__(256) void gemm_h(const float* __restrict__ x,
                                              const float* __restrict__ W,
                                              const float* __restrict__ aa,
                                              u16* __restrict__ hT,
                                              float* __restrict__ ssrc,
                                              float* __restrict__ sdst) {
    __shared__ float xs[32 * 128];
    __shared__ float Wsh[32 * 128];
    const int t = threadIdx.x;
    const int i0 = blockIdx.x * 32;
    const int c4 = (t & 31) * 4;
    const int r8 = t >> 5;

#pragma unroll
    for (int p = 0; p < 4; ++p) {
        int rr = p * 8 + r8;
        *(float4*)&xs[rr * 128 + c4] = *(const float4*)&x[(size_t)(i0 + rr) * 128 + c4];
    }

    const int tx = t & 31, ty = t >> 5;
    const int r0 = ty * 4, c0 = tx * 4;
    float acc[4][4] = {};

    for (int kc = 0; kc < 4; ++kc) {
        __syncthreads();
#pragma unroll
        for (int p = 0; p < 4; ++p) {
            int k = p * 8 + r8;
            *(float4*)&Wsh[k * 128 + c4] = *(const float4*)&W[(kc * 32 + k) * 128 + c4];
        }
        __syncthreads();
#pragma unroll 4
        for (int k = 0; k < 32; k += 4) {
            float xr[4][4];
#pragma unroll
            for (int rr = 0; rr < 4; ++rr)
                *(float4*)xr[rr] = *(const float4*)&xs[(r0 + rr) * 128 + kc * 32 + k];
#pragma unroll
            for (int kk = 0; kk < 4; ++kk) {
                float4 wv = *(const float4*)&Wsh[(k + kk) * 128 + c0];
#pragma unroll
                for (int rr = 0; rr < 4; ++rr) {
                    acc[rr][0] += xr[rr][kk] * wv.x;
                    acc[rr][1] += xr[rr][kk] * wv.y;
                    acc[rr][2] += xr[rr][kk] * wv.z;
                    acc[rr][3] += xr[rr][kk] * wv.w;
                }
            }
        }
    }

    // epilogue 1: hT bf16 transposed store (64B contiguous per (block,col) across ty/rr)
#pragma unroll
    for (int rr = 0; rr < 4; ++rr)
#pragma unroll
        for (int cc = 0; cc < 4; ++cc)
            hT[(size_t)(c0 + cc) * N + (i0 + r0 + rr)] = f2bf(acc[rr][cc]);

    // epilogue 2: fused scores s_src/s_dst from full-precision accumulators
    float4 asv = *(const float4*)&aa[c0];
    float4 adv = *(const float4*)&aa[F + c0];
#pragma unroll
    for (int rr = 0; rr < 4; ++rr) {
        float vs = acc[rr][0] * asv.x + acc[rr][1] * asv.y + acc[rr][2] * asv.z + acc[rr][3] * asv.w;
        float vd = acc[rr][0] * adv.x + acc[rr][1] * adv.y + acc[rr][2] * adv.z + acc[rr][3] * adv.w;
#pragma unroll
        for (int off = 16; off >= 1; off >>= 1) {
            vs += __shfl_down(vs, off, 32);
            vd += __shfl_down(vd, off, 32);
        }
        if (tx == 0) {
            ssrc[i0 + r0 + rr] = vs;
            sdst[i0 + r0 + rr] = vd;
        }
    }
}

// ---------------- K2: attention via bf16 MFMA, adj->A-frags computed in-lane ----------------
// Round-0 proven structure: block = 32 i-rows, 4 waves, 2 j-splits. Wave w produces
// A-frag-set (rt=w&1, ks=w>>1) directly from adj, consumes all 4 frag-sets for
// feature cols [w*32, w*32+32). Only change vs round 0: compute_write packs via
// v_cvt_pk_bf16_f32 (1 inst / 2 elems, RNE == f2bf — bit-identical) to shorten
// the serial VALU tail between barriers.
__global__ __launch_bounds__(256, 2) void attn_mfma(const int* __restrict__ adj,
                                                    const u16* __restrict__ hT,
                                                    const float* __restrict__ ssrc,
                                                    const float* __restrict__ sdst,
                                                    float* __restrict__ out,
                                                    float* __restrict__ pacc1,
                                                    float* __restrict__ pS) {
    __shared__ short8 wsh[2][4][64];   // 8 KB: [buf][frag-set rt*2+ks][lane]
    __shared__ float srow[2][2][16];

    const int t = threadIdx.x;
    const int w = t >> 6, L = t & 63;
    const int quad = L >> 4, l16 = L & 15;
    const int i0 = blockIdx.x * 32;
    const int split = blockIdx.y;
    const int jbase = split * (N / 2);
    const int NC = (N / 2) / 64;

    const int rt = w & 1, ks = w >> 1;
    const int fragid = rt * 2 + ks;
    const int prow = i0 + rt * 16 + l16;
    const float s_i = ssrc[prow];

    const int* pA = adj + (size_t)prow * N + jbase + ks * 32 + quad * 8;
    const float* pD = sdst + jbase + ks * 32 + quad * 8;
    const u16* pB = hT + (size_t)(w * 32 + l16) * N + jbase + quad * 8;

    f32x4 acc[2][2];
#pragma unroll
    for (int a = 0; a < 2; ++a)
#pragma unroll
        for (int b = 0; b < 2; ++b) acc[a][b] = 0.f;
    float rsum = 0.f;

    // compute 8 w values -> bf16 frag + rowsum (uses bf16-rounded values so S matches PV exactly)
    auto compute_write = [&](int buf, int4 a0, int4 a1, float4 d0, float4 d1) {
        const int m[8] = {a0.x, a0.y, a0.z, a0.w, a1.x, a1.y, a1.z, a1.w};
        const float d[8] = {d0.x, d0.y, d0.z, d0.w, d1.x, d1.y, d1.z, d1.w};
        float wv[8];
#pragma unroll
        for (int k = 0; k < 8; ++k) {
            float z = s_i + d[k];
            float e = __expf(lrelu(z));
            wv[k] = (m[k] > 0) ? e : 0.f;
        }
        union { unsigned int u[4]; short8 s8; } pk;
        float s = 0.f;
#pragma unroll
        for (int p = 0; p < 4; ++p) {
            unsigned int r;
            asm("v_cvt_pk_bf16_f32 %0, %1, %2" : "=v"(r) : "v"(wv[2 * p]), "v"(wv[2 * p + 1]));
            pk.u[p] = r;
            s += __uint_as_float(r << 16);          // bf2f(element 2p)
            s += __uint_as_float(r & 0xffff0000u);  // bf2f(element 2p+1)
        }
        rsum += s;
        wsh[buf][fragid][L] = pk.s8;
    };

    // ---- prologue: chunk 0 ----
    int4 aC0 = *(const int4*)(pA);
    int4 aC1 = *(const int4*)(pA + 4);
    float4 dC0 = *(const float4*)(pD);
    float4 dC1 = *(const float4*)(pD + 4);
    compute_write(0, aC0, aC1, dC0, dC1);

    short8 Bbuf[2][2];
#pragma unroll
    for (int c2 = 0; c2 < 2; ++c2)
#pragma unroll
        for (int kb = 0; kb < 2; ++kb)
            Bbuf[c2][kb] = *(const short8*)(pB + (size_t)c2 * 16 * N + kb * 32);

    // prefetch chunk 1 adj/sdst
    int4 aN0 = *(const int4*)(pA + 64);
    int4 aN1 = *(const int4*)(pA + 64 + 4);
    float4 dN0 = *(const float4*)(pD + 64);
    float4 dN1 = *(const float4*)(pD + 64 + 4);

    for (int c = 1; c < NC; ++c) {
        __syncthreads();  // wsh[(c-1)&1] ready; buf (c&1) readers (chunk c-2) long done
        const int coff = c * 64;

        // B(c) loads in flight across this iteration (consumed next iter / epilogue)
        short8 Bload[2][2];
#pragma unroll
        for (int c2 = 0; c2 < 2; ++c2)
#pragma unroll
            for (int kb = 0; kb < 2; ++kb)
                Bload[c2][kb] = *(const short8*)(pB + (size_t)c2 * 16 * N + kb * 32 + coff);

        // prefetch adj/sdst for chunk c+1 (clamped; redundant final load is harmless)
        const int cn = (c + 1 < NC) ? c + 1 : NC - 1;
        int4 aP0 = *(const int4*)(pA + cn * 64);
        int4 aP1 = *(const int4*)(pA + cn * 64 + 4);
        float4 dP0 = *(const float4*)(pD + cn * 64);
        float4 dP1 = *(const float4*)(pD + cn * 64 + 4);

        // MFMA chunk c-1
        short8 af[4];
#pragma unroll
        for (int fs = 0; fs < 4; ++fs) af[fs] = wsh[(c - 1) & 1][fs][L];
#pragma unroll
        for (int c2 = 0; c2 < 2; ++c2)
#pragma unroll
            for (int rc = 0; rc < 2; ++rc)
#pragma unroll
                for (int kb = 0; kb < 2; ++kb)
                    acc[c2][rc] = __builtin_amdgcn_mfma_f32_16x16x32_bf16(
                        af[rc * 2 + kb], Bbuf[c2][kb], acc[c2][rc], 0, 0, 0);

        // w(c) from regs loaded last iteration
        compute_write(c & 1, aN0, aN1, dN0, dN1);

        // rotate
        aN0 = aP0; aN1 = aP1; dN0 = dP0; dN1 = dP1;
#pragma unroll
        for (int c2 = 0; c2 < 2; ++c2)
#pragma unroll
            for (int kb = 0; kb < 2; ++kb) Bbuf[c2][kb] = Bload[c2][kb];
    }

    // ---- epilogue: MFMA last chunk ----
    __syncthreads();
    {
        short8 af[4];
#pragma unroll
        for (int fs = 0; fs < 4; ++fs) af[fs] = wsh[(NC - 1) & 1][fs][L];
#pragma unroll
        for (int c2 = 0; c2 < 2; ++c2)
#pragma unroll
            for (int rc = 0; rc < 2; ++rc)
#pragma unroll
                for (int kb = 0; kb < 2; ++kb)
                    acc[c2][rc] = __builtin_amdgcn_mfma_f32_16x16x32_bf16(
                        af[rc * 2 + kb], Bbuf[c2][kb], acc[c2][rc], 0, 0, 0);
    }

    // store partials: D layout col=lane&15, row=quad*4+reg
    float* dst = split ? pacc1 : out;
#pragma unroll
    for (int c2 = 0; c2 < 2; ++c2) {
        const int col = (w * 2 + c2) * 16 + l16;
#pragma unroll
        for (int rc = 0; rc < 2; ++rc) {
            const int row0 = i0 + rc * 16 + quad * 4;
#pragma unroll
            for (int r = 0; r < 4; ++r)
                dst[(size_t)(row0 + r) * F + col] = acc[c2][rc][r];
        }
    }

    // row sums: butterfly over quads, then combine the two ks-waves via LDS
    rsum += __shfl_xor(rsum, 16);
    rsum += __shfl_xor(rsum, 32);
    if (L < 16) srow[rt][ks][l16] = rsum;
    __syncthreads();
    if (t < 32) pS[split * N + i0 + t] = srow[t >> 4][0][t & 15] + srow[t >> 4][1][t & 15];
}

// ---------------- K3: out = (out + pacc1) / (pS0 + pS1) ----------------
__global__ __launch_bounds__(256) void finalize(float* __restrict__ out,
                                                const float* __restrict__ pacc1,
                                                const float* __restrict__ pS) {
    const int idx = (blockIdx.x * 256 + threadIdx.x) * 4;
    const int i = idx >> 7;
    const float inv = 1.0f / (pS[i] + pS[N + i]);
    float4 a0 = *(const float4*)&out[idx];
    float4 a1 = *(const float4*)&pacc1[idx];
    float4 o = {(a0.x + a1.x) * inv, (a0.y + a1.y) * inv,
                (a0.z + a1.z) * inv, (a0.w + a1.w) * inv};
    *(float4*)&out[idx] = o;
}

extern "C" void kernel_launch(void* const* d_in, const int* in_sizes, int n_in,
                              void* d_out, int out_size, void* d_ws, size_t ws_size,
                              hipStream_t stream) {
    (void)in_sizes; (void)n_in; (void)out_size; (void)ws_size;
    const float* x   = (const float*)d_in[0];
    const int*   adj = (const int*)d_in[1];
    const float* W   = (const float*)d_in[2];
    const float* a   = (const float*)d_in[3];
    float* out = (float*)d_out;

    u16* hT     = (u16*)d_ws;                    // N*F bf16 (2 MB)
    float* ssrc = (float*)(hT + (size_t)N * F);  // N
    float* sdst = ssrc + N;                      // N
    float* pS   = sdst + N;                      // 2N
    float* pacc1 = pS + 2 * N;                   // N*F fp32 (4 MB)

    gemm_h<<<N / 32, 256, 0, stream>>>(x, W, a, hT, ssrc, sdst);
    attn_mfma<<<dim3(N / 32, 2), 256, 0, stream>>>(adj, hT, ssrc, sdst, out, pacc1, pS);
    finalize<<<(N * F / 4) / 256, 256, 0, stream>>>(out, pacc1, pS);
}